// Round 6
// baseline (27.698 us; speedup 1.0000x reference)
//
#include <hip/hip_runtime.h>

// Problem constants (fixed by reference shapes)
#define NB 2        // batch
#define BB 257      // bins
#define PB 256      // centers = bins-1
#define LL 16       // patches per image (4x4)
#define QQ 12544    // points per patch (112*112)
#define KP 112      // patch size
#define WIMG 448    // image width
#define SPLIT 7     // slices per patch; QS = 12544/7 = 1792 = 7*256 exactly
#define QS 1792
#define VPT 7       // points per thread (exact)
#define NPATCH (NB*LL)          // 32
#define NBLK (NPATCH*SPLIT)     // 224 blocks
#define BIGV 1e10f
#define SENT_LO (-2e18f)
#define SENT_HI ( 2e18f)

// ws layout (u32 slots)
#define LO_OFF  0                       // 32*256 u32, memset 0x00 each call
#define HI_OFF  (NPATCH*PB)             // 32*256 u32, memset 0xFF each call
#define CS_OFF  (2*NPATCH*PB)           // 32*256 f32 sorted centers (written by sl==0 blocks)
#define SUM_OFF (3*NPATCH*PB)           // 224 f32 per-slice sumY
#define CNT_OFF (3*NPATCH*PB + NBLK)    // 224 f32 per-slice count

// monotone float<->uint mapping: uint order == float order
__device__ __forceinline__ unsigned encf(float f) {
    unsigned u = __float_as_uint(f);
    return (u >> 31) ? ~u : (u | 0x80000000u);
}
__device__ __forceinline__ float decf(unsigned e) {
    return __uint_as_float((e >> 31) ? (e & 0x7fffffffu) : ~e);
}
__device__ __forceinline__ unsigned umaxu(unsigned a, unsigned b){ return a > b ? a : b; }
__device__ __forceinline__ unsigned uminu(unsigned a, unsigned b){ return a < b ? a : b; }
// NaN-safe: untouched lo (0x00000000) / hi (0xFFFFFFFF) decode to NaN;
// fminf picks the non-NaN operand, so the valid side wins.
__device__ __forceinline__ float nn_term(float c, unsigned lo, unsigned hi) {
    float a = c - decf(lo);
    float b = decf(hi) - c;
    return fminf(a*a, b*b);
}

// ---- kernel 1: 224 blocks; rank sort + searches + LDS merge + global atomic merge ----
__global__ __launch_bounds__(256) void chamfer_slices(const float* __restrict__ bins,
                                                      const float* __restrict__ img,
                                                      unsigned* __restrict__ ws) {
    __shared__ __align__(16) float tmp[PB];
    __shared__ __align__(16) float cs[PB];
    __shared__ unsigned lop[PB], hih[PB];
    __shared__ float rs[4], rc[4];

    float* wsf = (float*)ws;
    const int bid = blockIdx.x;
    const int g  = bid / SPLIT;          // patch id 0..31
    const int sl = bid % SPLIT;
    const int n = g / LL, l = g % LL;
    const int t = threadIdx.x;
    const int wid = t >> 6, lane = t & 63;
    const unsigned ELO = encf(SENT_LO), EHI = encf(SENT_HI);

    // centers + LDS init
    float c;
    {
        float b0 = bins[(n*BB + t    )*LL + l];
        float b1 = bins[(n*BB + t + 1)*LL + l];
        c = 0.5f * (b0 + b1);
    }
    tmp[t] = c;
    lop[t] = ELO;
    hih[t] = EHI;
    __syncthreads();

    // rank sort (stable via index tie-break), ascending into cs
    {
        int rank = 0;
        const float4* t4 = reinterpret_cast<const float4*>(tmp);
        #pragma unroll 16
        for (int j = 0; j < 64; ++j) {
            float4 q = t4[j];
            int b = 4*j;
            rank += (q.x < c || (q.x == c && (b+0) < t)) ? 1 : 0;
            rank += (q.y < c || (q.y == c && (b+1) < t)) ? 1 : 0;
            rank += (q.z < c || (q.z == c && (b+2) < t)) ? 1 : 0;
            rank += (q.w < c || (q.w == c && (b+3) < t)) ? 1 : 0;
        }
        cs[rank] = c;
    }
    __syncthreads();

    // slice 0 publishes sorted centers for the merge kernel
    if (sl == 0) wsf[CS_OFF + g*PB + t] = cs[t];

    // my 7 points; independent branchless lower_bound chains (ILP)
    const float* pimg = img + n*WIMG*WIMG + (l >> 2)*KP*WIMG + (l & 3)*KP;
    float v[VPT]; int u[VPT];
    #pragma unroll
    for (int k = 0; k < VPT; ++k) {
        int q = sl*QS + t + k*256;
        int ki = q / KP, kj = q - ki*KP;
        v[k] = pimg[ki*WIMG + kj];
    }
    #pragma unroll
    for (int k = 0; k < VPT; ++k) {
        float x = v[k]; int uu = 0;
        #pragma unroll
        for (int stp = 128; stp; stp >>= 1)
            uu += (cs[uu + stp - 1] < x) ? stp : 0;
        uu += (cs[PB-1] < x) ? 1 : 0;
        u[k] = uu;
    }

    // chamfer y->x partials + lo/hi candidate LDS atomics
    float ls = 0.f, lc = 0.f;
    #pragma unroll
    for (int k = 0; k < VPT; ++k) {
        float x = v[k];
        if (x > 0.f) {
            int uu = u[k];
            float dmin = BIGV;
            if (uu > 0)  { float d = x - cs[uu-1]; dmin = d*d;              atomicMin(&hih[uu-1], encf(x)); }
            if (uu < PB) { float d = cs[uu] - x;   dmin = fminf(dmin, d*d); atomicMax(&lop[uu],  encf(x)); }
            ls += dmin;
            lc += 1.f;
        }
    }
    #pragma unroll
    for (int m = 32; m; m >>= 1) { ls += __shfl_xor(ls, m); lc += __shfl_xor(lc, m); }
    if (lane == 0) { rs[wid] = ls; rc[wid] = lc; }
    __syncthreads();

    // global merges: order-independent atomics -> deterministic
    unsigned lv = lop[t];
    if (lv != ELO) atomicMax(&ws[LO_OFF + g*PB + t], lv);
    unsigned hv = hih[t];
    if (hv != EHI) atomicMin(&ws[HI_OFF + g*PB + t], hv);
    if (t == 0) {
        wsf[SUM_OFF + bid] = rs[0]+rs[1]+rs[2]+rs[3];
        wsf[CNT_OFF + bid] = rc[0]+rc[1]+rc[2]+rc[3];
    }
}

// ---- kernel 2: one block; per-patch wave scans + chamfer x->y + final mean ----
__global__ __launch_bounds__(1024) void final_merge(const unsigned* __restrict__ ws,
                                                    float* __restrict__ out) {
    const float* wsf = (const float*)ws;
    const int t = threadIdx.x;
    const int w = t >> 6, lane = t & 63;   // 16 waves; wave w handles patches w, w+16
    __shared__ float pp[NPATCH];

    for (int g = w; g < NPATCH; g += 16) {
        uint4  lp = reinterpret_cast<const uint4*>(ws + LO_OFF)[g*64 + lane];
        uint4  hp = reinterpret_cast<const uint4*>(ws + HI_OFF)[g*64 + lane];
        float4 cv = reinterpret_cast<const float4*>(wsf + CS_OFF)[g*64 + lane];

        // prefix-max (encoded): serial-4 then wave scan
        unsigned p0 = lp.x, p1 = umaxu(p0, lp.y), p2 = umaxu(p1, lp.z), p3 = umaxu(p2, lp.w);
        unsigned inc = p3;
        #pragma unroll
        for (int d = 1; d < 64; d <<= 1) {
            unsigned o = __shfl_up(inc, d);
            if (lane >= d) inc = umaxu(inc, o);
        }
        unsigned ex = __shfl_up(inc, 1);
        if (lane == 0) ex = 0u;                      // -inf sentinel (encoded)
        unsigned lo0 = umaxu(ex,p0), lo1 = umaxu(ex,p1), lo2 = umaxu(ex,p2), lo3 = umaxu(ex,p3);

        // suffix-min (encoded)
        unsigned s3 = hp.w, s2 = uminu(hp.z, s3), s1 = uminu(hp.y, s2), s0 = uminu(hp.x, s1);
        unsigned incs = s0;
        #pragma unroll
        for (int d = 1; d < 64; d <<= 1) {
            unsigned o = __shfl_down(incs, d);
            if (lane + d < 64) incs = uminu(incs, o);
        }
        unsigned exh = __shfl_down(incs, 1);
        if (lane == 63) exh = 0xFFFFFFFFu;           // +inf sentinel (encoded)
        unsigned hi0 = uminu(exh,s0), hi1 = uminu(exh,s1), hi2 = uminu(exh,s2), hi3 = uminu(exh,s3);

        float sum = nn_term(cv.x, lo0, hi0) + nn_term(cv.y, lo1, hi1)
                  + nn_term(cv.z, lo2, hi2) + nn_term(cv.w, lo3, hi3);
        #pragma unroll
        for (int m = 32; m; m >>= 1) sum += __shfl_xor(sum, m);

        if (lane == 0) {
            float sy = 0.f, cy = 0.f;
            #pragma unroll
            for (int s = 0; s < SPLIT; ++s) {
                sy += wsf[SUM_OFF + g*SPLIT + s];
                cy += wsf[CNT_OFF + g*SPLIT + s];
            }
            float chx = sum * (1.0f / PB);
            float chy = sy / fmaxf(cy, 1.f);
            pp[g] = (cy > 0.5f) ? (chx + chy) : 0.f;
        }
    }
    __syncthreads();
    if (t < 64) {
        float val = (lane < NPATCH) ? pp[lane] : 0.f;
        #pragma unroll
        for (int m = 32; m; m >>= 1) val += __shfl_xor(val, m);
        if (lane == 0) out[0] = val * (1.0f / NPATCH);
    }
}

extern "C" void kernel_launch(void* const* d_in, const int* in_sizes, int n_in,
                              void* d_out, int out_size, void* d_ws, size_t ws_size,
                              hipStream_t stream) {
    const float* bins = (const float*)d_in[0];
    const float* img  = (const float*)d_in[1];
    unsigned* ws = (unsigned*)d_ws;
    float* out = (float*)d_out;
    (void)in_sizes; (void)n_in; (void)out_size; (void)ws_size;

    // init merge arrays: lo = 0x00 (-inf encoded-ish), hi = 0xFF (+inf encoded-ish)
    hipMemsetAsync(ws + LO_OFF, 0x00, NPATCH*PB*sizeof(unsigned), stream);
    hipMemsetAsync(ws + HI_OFF, 0xFF, NPATCH*PB*sizeof(unsigned), stream);
    hipLaunchKernelGGL(chamfer_slices, dim3(NBLK), dim3(256),  0, stream, bins, img, ws);
    hipLaunchKernelGGL(final_merge,    dim3(1),    dim3(1024), 0, stream, ws, out);
}

// Round 7
// 21.830 us; speedup vs baseline: 1.2688x; 1.2688x over previous
//
#include <hip/hip_runtime.h>

// Problem constants (fixed by reference shapes)
#define NB 2        // batch
#define BB 257      // bins
#define PB 256      // centers = bins-1
#define LL 16       // patches per image (4x4)
#define QQ 12544    // points per patch (112*112)
#define KP 112      // patch size
#define WIMG 448    // image width
#define SPLIT 7     // slices per patch; QS = 12544/7 = 1792 = 7*256 exactly
#define QS 1792
#define VPT 7       // points per thread (exact)
#define NPATCH (NB*LL)          // 32
#define NBLK (NPATCH*SPLIT)     // 224 blocks
#define BIGV 1e10f
#define SENT_LO (-2e18f)
#define SENT_HI ( 2e18f)

// ws layout (f32 slots) — all plain stores, no init required
#define DS_OFF  0                    // NBLK*PB: per-slice per-center nearest-dist^2
#define SUM_OFF (NBLK*PB)            // NBLK: per-slice sumY
#define CNT_OFF (NBLK*PB + NBLK)     // NBLK: per-slice count

// monotone float<->uint mapping: uint order == float order (all values finite here)
__device__ __forceinline__ unsigned encf(float f) {
    unsigned u = __float_as_uint(f);
    return (u >> 31) ? ~u : (u | 0x80000000u);
}
__device__ __forceinline__ float decf(unsigned e) {
    return __uint_as_float((e >> 31) ? (e & 0x7fffffffu) : ~e);
}
__device__ __forceinline__ unsigned umaxu(unsigned a, unsigned b){ return a > b ? a : b; }
__device__ __forceinline__ unsigned uminu(unsigned a, unsigned b){ return a < b ? a : b; }
__device__ __forceinline__ float nn_term(float c, unsigned lo, unsigned hi) {
    float a = c - decf(lo);   // sentinels are finite (+-2e18) -> a*a ~ 4e36, loses every min
    float b = decf(hi) - c;
    return fminf(a*a, b*b);
}

// ---- kernel 1: 224 blocks; sort + search + in-block scan -> per-slice min-dist ----
__global__ __launch_bounds__(256) void chamfer_slice(const float* __restrict__ bins,
                                                     const float* __restrict__ img,
                                                     float* __restrict__ wsf) {
    __shared__ __align__(16) float tmp[PB];
    __shared__ __align__(16) float cs[PB];
    __shared__ unsigned lop[PB], hih[PB];
    __shared__ float rs[4], rc[4];

    const int bid = blockIdx.x;
    const int g  = bid / SPLIT;          // patch id 0..31
    const int sl = bid % SPLIT;
    const int n = g / LL, l = g % LL;
    const int t = threadIdx.x;
    const int wid = t >> 6, lane = t & 63;
    const unsigned ELO = encf(SENT_LO), EHI = encf(SENT_HI);

    // centers + LDS init
    float c;
    {
        float b0 = bins[(n*BB + t    )*LL + l];
        float b1 = bins[(n*BB + t + 1)*LL + l];
        c = 0.5f * (b0 + b1);
    }
    tmp[t] = c;
    lop[t] = ELO;
    hih[t] = EHI;
    __syncthreads();

    // rank sort (stable via index tie-break), ascending into cs (broadcast LDS reads)
    {
        int rank = 0;
        const float4* t4 = reinterpret_cast<const float4*>(tmp);
        #pragma unroll 16
        for (int j = 0; j < 64; ++j) {
            float4 q = t4[j];
            int b = 4*j;
            rank += (q.x < c || (q.x == c && (b+0) < t)) ? 1 : 0;
            rank += (q.y < c || (q.y == c && (b+1) < t)) ? 1 : 0;
            rank += (q.z < c || (q.z == c && (b+2) < t)) ? 1 : 0;
            rank += (q.w < c || (q.w == c && (b+3) < t)) ? 1 : 0;
        }
        cs[rank] = c;
    }
    __syncthreads();

    // my 7 points; independent branchless lower_bound chains (ILP)
    const float* pimg = img + n*WIMG*WIMG + (l >> 2)*KP*WIMG + (l & 3)*KP;
    float v[VPT]; int u[VPT];
    #pragma unroll
    for (int k = 0; k < VPT; ++k) {
        int q = sl*QS + t + k*256;
        int ki = q / KP, kj = q - ki*KP;
        v[k] = pimg[ki*WIMG + kj];
    }
    #pragma unroll
    for (int k = 0; k < VPT; ++k) {
        float x = v[k]; int uu = 0;
        #pragma unroll
        for (int stp = 128; stp; stp >>= 1)
            uu += (cs[uu + stp - 1] < x) ? stp : 0;
        uu += (cs[PB-1] < x) ? 1 : 0;
        u[k] = uu;
    }

    // chamfer y->x partials + lo/hi candidate LDS atomics
    float ls = 0.f, lc = 0.f;
    #pragma unroll
    for (int k = 0; k < VPT; ++k) {
        float x = v[k];
        if (x > 0.f) {
            int uu = u[k];
            float dmin = BIGV;
            if (uu > 0)  { float d = x - cs[uu-1]; dmin = d*d;              atomicMin(&hih[uu-1], encf(x)); }
            if (uu < PB) { float d = cs[uu] - x;   dmin = fminf(dmin, d*d); atomicMax(&lop[uu],  encf(x)); }
            ls += dmin;
            lc += 1.f;
        }
    }
    #pragma unroll
    for (int m = 32; m; m >>= 1) { ls += __shfl_xor(ls, m); lc += __shfl_xor(lc, m); }
    if (lane == 0) { rs[wid] = ls; rc[wid] = lc; }
    __syncthreads();   // publishes rs/rc AND all LDS candidate atomics

    if (t == 0) {
        wsf[SUM_OFF + bid] = rs[0]+rs[1]+rs[2]+rs[3];
        wsf[CNT_OFF + bid] = rc[0]+rc[1]+rc[2]+rc[3];
    }

    // wave 0: prefix-max / suffix-min scan over this slice's candidates,
    // emit per-center nearest-dist^2 (256 floats, plain stores)
    if (wid == 0) {
        uint4  lp = reinterpret_cast<const uint4*>(lop)[lane];
        uint4  hp = reinterpret_cast<const uint4*>(hih)[lane];
        float4 cv = reinterpret_cast<const float4*>(cs)[lane];

        unsigned p0 = lp.x, p1 = umaxu(p0, lp.y), p2 = umaxu(p1, lp.z), p3 = umaxu(p2, lp.w);
        unsigned inc = p3;
        #pragma unroll
        for (int d = 1; d < 64; d <<= 1) {
            unsigned o = __shfl_up(inc, d);
            if (lane >= d) inc = umaxu(inc, o);
        }
        unsigned ex = __shfl_up(inc, 1);
        if (lane == 0) ex = ELO;
        unsigned lo0 = umaxu(ex,p0), lo1 = umaxu(ex,p1), lo2 = umaxu(ex,p2), lo3 = umaxu(ex,p3);

        unsigned s3 = hp.w, s2 = uminu(hp.z, s3), s1 = uminu(hp.y, s2), s0 = uminu(hp.x, s1);
        unsigned incs = s0;
        #pragma unroll
        for (int d = 1; d < 64; d <<= 1) {
            unsigned o = __shfl_down(incs, d);
            if (lane + d < 64) incs = uminu(incs, o);
        }
        unsigned exh = __shfl_down(incs, 1);
        if (lane == 63) exh = EHI;
        unsigned hi0 = uminu(exh,s0), hi1 = uminu(exh,s1), hi2 = uminu(exh,s2), hi3 = uminu(exh,s3);

        float4 dd;
        dd.x = nn_term(cv.x, lo0, hi0);
        dd.y = nn_term(cv.y, lo1, hi1);
        dd.z = nn_term(cv.z, lo2, hi2);
        dd.w = nn_term(cv.w, lo3, hi3);
        reinterpret_cast<float4*>(wsf + DS_OFF)[bid*64 + lane] = dd;
    }
}

// ---- kernel 2: one block; 7-way min-merge per patch + chamfer sums + mean ----
__global__ __launch_bounds__(1024) void final_merge(const float* __restrict__ wsf,
                                                    float* __restrict__ out) {
    __shared__ float pp[NPATCH];
    const int t = threadIdx.x;
    const int w = t >> 6, lane = t & 63;   // 16 waves; wave w handles patches w, w+16

    const float4* d4 = reinterpret_cast<const float4*>(wsf + DS_OFF);
    for (int g = w; g < NPATCH; g += 16) {
        float4 m = d4[(g*SPLIT)*64 + lane];
        #pragma unroll
        for (int s = 1; s < SPLIT; ++s) {
            float4 q = d4[(g*SPLIT + s)*64 + lane];
            m.x = fminf(m.x, q.x); m.y = fminf(m.y, q.y);
            m.z = fminf(m.z, q.z); m.w = fminf(m.w, q.w);
        }
        float sum = (m.x + m.y) + (m.z + m.w);
        #pragma unroll
        for (int d = 32; d; d >>= 1) sum += __shfl_xor(sum, d);

        if (lane == 0) {
            float sy = 0.f, cy = 0.f;
            #pragma unroll
            for (int s = 0; s < SPLIT; ++s) {
                sy += wsf[SUM_OFF + g*SPLIT + s];
                cy += wsf[CNT_OFF + g*SPLIT + s];
            }
            float chx = sum * (1.0f / PB);
            float chy = sy / fmaxf(cy, 1.f);
            pp[g] = (cy > 0.5f) ? (chx + chy) : 0.f;
        }
    }
    __syncthreads();
    if (t < 64) {
        float val = (lane < NPATCH) ? pp[lane] : 0.f;
        #pragma unroll
        for (int m = 32; m; m >>= 1) val += __shfl_xor(val, m);
        if (lane == 0) out[0] = val * (1.0f / NPATCH);
    }
}

extern "C" void kernel_launch(void* const* d_in, const int* in_sizes, int n_in,
                              void* d_out, int out_size, void* d_ws, size_t ws_size,
                              hipStream_t stream) {
    const float* bins = (const float*)d_in[0];
    const float* img  = (const float*)d_in[1];
    float* wsf = (float*)d_ws;
    float* out = (float*)d_out;
    (void)in_sizes; (void)n_in; (void)out_size; (void)ws_size;

    hipLaunchKernelGGL(chamfer_slice, dim3(NBLK), dim3(256),  0, stream, bins, img, wsf);
    hipLaunchKernelGGL(final_merge,   dim3(1),    dim3(1024), 0, stream, wsf, out);
}